// Round 1
// baseline (3183.761 us; speedup 1.0000x reference)
//
#include <hip/hip_runtime.h>
#include <math.h>

#define HW 2304
#define NB 8
#define CH 256
#define QC 512
#define NH 4
#define DK 32
#define DV 64
#define EPS 1e-3f
#define JT 16

// ---------------- Kernel A: qkv = BN(conv1x1(x, qkv_w)) ----------------
// grid (HW/256=9, QC/8=64, NB), block 256
__global__ __launch_bounds__(256) void qkv_conv(
    const float* __restrict__ x, const float* __restrict__ w,
    const float* __restrict__ g, const float* __restrict__ bt,
    const float* __restrict__ mn, const float* __restrict__ vr,
    float* __restrict__ out)
{
  __shared__ float ws[8][CH];
  const int t = threadIdx.x;
  const int co0 = blockIdx.y * 8;
  const int b = blockIdx.z;
  const int p = blockIdx.x * 256 + t;
  #pragma unroll
  for (int r = 0; r < 8; ++r) ws[r][t] = w[(size_t)(co0 + r) * CH + t];
  __syncthreads();
  const float* xb = x + ((size_t)b * CH) * HW + p;
  float acc[8] = {0.f,0.f,0.f,0.f,0.f,0.f,0.f,0.f};
  for (int ci = 0; ci < CH; ci += 4) {
    const float x0 = xb[(size_t)(ci + 0) * HW];
    const float x1 = xb[(size_t)(ci + 1) * HW];
    const float x2 = xb[(size_t)(ci + 2) * HW];
    const float x3 = xb[(size_t)(ci + 3) * HW];
    #pragma unroll
    for (int r = 0; r < 8; ++r) {
      const float4 wv = *reinterpret_cast<const float4*>(&ws[r][ci]);
      acc[r] = fmaf(wv.x, x0, acc[r]);
      acc[r] = fmaf(wv.y, x1, acc[r]);
      acc[r] = fmaf(wv.z, x2, acc[r]);
      acc[r] = fmaf(wv.w, x3, acc[r]);
    }
  }
  #pragma unroll
  for (int r = 0; r < 8; ++r) {
    const int co = co0 + r;
    const float s = g[co] / sqrtf(vr[co] + EPS);
    out[((size_t)b * QC + co) * HW + p] = acc[r] * s + (bt[co] - mn[co] * s);
  }
}

// ---------------- Kernel B: flash attention (fp32 baseline) ----------------
// qkv layout (b, 512, 2304); per head h: q ch = h*128+[0,32), k = h*128+[32,64),
// v = h*128+[64,128). out[d][i] = sum_j v[d][j] * softmax_j(scale * q^T k)[i][j]
// grid (9, NH, NB), block 256; 1 thread = 1 query row i.
__global__ __launch_bounds__(256) void flash_attn(
    const float* __restrict__ qkv, float* __restrict__ out)
{
  __shared__ float Kt[DK * JT];
  __shared__ float Vt[DV * JT];
  const int t = threadIdx.x;
  const int h = blockIdx.y;
  const int b = blockIdx.z;
  const int i = blockIdx.x * 256 + t;
  const float scale = 0.17677669529663687f;  // 32^-0.5
  const float* base = qkv + ((size_t)b * QC + h * 128) * HW;

  float q[DK];
  #pragma unroll
  for (int k = 0; k < DK; ++k) q[k] = base[(size_t)k * HW + i] * scale;

  float m = -INFINITY, l = 0.f;
  float acc[DV];
  #pragma unroll
  for (int d = 0; d < DV; ++d) acc[d] = 0.f;

  for (int j0 = 0; j0 < HW; j0 += JT) {
    __syncthreads();
    // stage K tile (DK x JT = 512 floats) and V tile (DV x JT = 1024 floats)
    #pragma unroll
    for (int r = 0; r < 2; ++r) {
      const int e = t + 256 * r;
      const int j = e & (JT - 1), k = e >> 4;
      Kt[e] = base[(size_t)(DK + k) * HW + j0 + j];
    }
    #pragma unroll
    for (int r = 0; r < 4; ++r) {
      const int e = t + 256 * r;
      const int j = e & (JT - 1), d = e >> 4;
      Vt[e] = base[(size_t)(2 * DK + d) * HW + j0 + j];
    }
    __syncthreads();

    float s[JT];
    #pragma unroll
    for (int j = 0; j < JT; ++j) s[j] = 0.f;
    #pragma unroll
    for (int k = 0; k < DK; ++k) {
      const float qk = q[k];
      #pragma unroll
      for (int j4 = 0; j4 < JT / 4; ++j4) {
        const float4 kv = *reinterpret_cast<const float4*>(&Kt[k * JT + j4 * 4]);
        s[j4 * 4 + 0] = fmaf(qk, kv.x, s[j4 * 4 + 0]);
        s[j4 * 4 + 1] = fmaf(qk, kv.y, s[j4 * 4 + 1]);
        s[j4 * 4 + 2] = fmaf(qk, kv.z, s[j4 * 4 + 2]);
        s[j4 * 4 + 3] = fmaf(qk, kv.w, s[j4 * 4 + 3]);
      }
    }
    float tmax = s[0];
    #pragma unroll
    for (int j = 1; j < JT; ++j) tmax = fmaxf(tmax, s[j]);
    const float mn2 = fmaxf(m, tmax);
    const float corr = __expf(m - mn2);  // exp(-inf)=0 on first tile
    m = mn2;
    l *= corr;
    #pragma unroll
    for (int d = 0; d < DV; ++d) acc[d] *= corr;
    float ps = 0.f;
    #pragma unroll
    for (int j = 0; j < JT; ++j) { s[j] = __expf(s[j] - mn2); ps += s[j]; }
    l += ps;
    #pragma unroll
    for (int d = 0; d < DV; ++d) {
      float a = acc[d];
      #pragma unroll
      for (int j4 = 0; j4 < JT / 4; ++j4) {
        const float4 vv = *reinterpret_cast<const float4*>(&Vt[d * JT + j4 * 4]);
        a = fmaf(s[j4 * 4 + 0], vv.x, a);
        a = fmaf(s[j4 * 4 + 1], vv.y, a);
        a = fmaf(s[j4 * 4 + 2], vv.z, a);
        a = fmaf(s[j4 * 4 + 3], vv.w, a);
      }
      acc[d] = a;
    }
  }
  const float inv = 1.f / l;
  float* ob = out + ((size_t)b * CH + h * DV) * HW + i;
  #pragma unroll
  for (int d = 0; d < DV; ++d) ob[(size_t)d * HW] = acc[d] * inv;
}

// ------------- Kernel C: io += BN(dwconv3x3(v)) (in-place add) -------------
// grid (9, CH, NB), block 256
__global__ __launch_bounds__(256) void dwconv_add(
    const float* __restrict__ qkv, const float* __restrict__ w,
    const float* __restrict__ g, const float* __restrict__ bt,
    const float* __restrict__ mn, const float* __restrict__ vr,
    float* __restrict__ io)
{
  const int t = threadIdx.x;
  const int p = blockIdx.x * 256 + t;
  const int c = blockIdx.y;
  const int b = blockIdx.z;
  const int y = p / 48, xx = p - y * 48;
  const int vch = (c >> 6) * 128 + 64 + (c & 63);  // head*128 + 64 + d
  const float* in = qkv + ((size_t)b * QC + vch) * HW;
  const float* wc = w + c * 9;
  float a = 0.f;
  #pragma unroll
  for (int ky = 0; ky < 3; ++ky) {
    const int yy = y + ky - 1;
    if (yy < 0 || yy >= 48) continue;
    #pragma unroll
    for (int kx = 0; kx < 3; ++kx) {
      const int x2 = xx + kx - 1;
      if (x2 < 0 || x2 >= 48) continue;
      a = fmaf(wc[ky * 3 + kx], in[yy * 48 + x2], a);
    }
  }
  const float s = g[c] / sqrtf(vr[c] + EPS);
  const size_t o = ((size_t)b * CH + c) * HW + p;
  io[o] += a * s + (bt[c] - mn[c] * s);
}

// ---------------- Kernel D: out = BN(conv1x1(io, c2_w)) ----------------
// grid (9, CH/8=32, NB), block 256
__global__ __launch_bounds__(256) void c2_conv(
    const float* __restrict__ in, const float* __restrict__ w,
    const float* __restrict__ g, const float* __restrict__ bt,
    const float* __restrict__ mn, const float* __restrict__ vr,
    float* __restrict__ out)
{
  __shared__ float ws[8][CH];
  const int t = threadIdx.x;
  const int co0 = blockIdx.y * 8;
  const int b = blockIdx.z;
  const int p = blockIdx.x * 256 + t;
  #pragma unroll
  for (int r = 0; r < 8; ++r) ws[r][t] = w[(size_t)(co0 + r) * CH + t];
  __syncthreads();
  const float* xb = in + ((size_t)b * CH) * HW + p;
  float acc[8] = {0.f,0.f,0.f,0.f,0.f,0.f,0.f,0.f};
  for (int ci = 0; ci < CH; ci += 4) {
    const float x0 = xb[(size_t)(ci + 0) * HW];
    const float x1 = xb[(size_t)(ci + 1) * HW];
    const float x2 = xb[(size_t)(ci + 2) * HW];
    const float x3 = xb[(size_t)(ci + 3) * HW];
    #pragma unroll
    for (int r = 0; r < 8; ++r) {
      const float4 wv = *reinterpret_cast<const float4*>(&ws[r][ci]);
      acc[r] = fmaf(wv.x, x0, acc[r]);
      acc[r] = fmaf(wv.y, x1, acc[r]);
      acc[r] = fmaf(wv.z, x2, acc[r]);
      acc[r] = fmaf(wv.w, x3, acc[r]);
    }
  }
  #pragma unroll
  for (int r = 0; r < 8; ++r) {
    const int co = co0 + r;
    const float s = g[co] / sqrtf(vr[co] + EPS);
    out[((size_t)b * CH + co) * HW + p] = acc[r] * s + (bt[co] - mn[co] * s);
  }
}

extern "C" void kernel_launch(void* const* d_in, const int* in_sizes, int n_in,
                              void* d_out, int out_size, void* d_ws, size_t ws_size,
                              hipStream_t stream)
{
  const float* x     = (const float*)d_in[0];
  const float* qkv_w = (const float*)d_in[1];
  const float* qkv_g = (const float*)d_in[2];
  const float* qkv_b = (const float*)d_in[3];
  const float* qkv_m = (const float*)d_in[4];
  const float* qkv_v = (const float*)d_in[5];
  const float* c1_w  = (const float*)d_in[6];
  const float* c1_g  = (const float*)d_in[7];
  const float* c1_b  = (const float*)d_in[8];
  const float* c1_m  = (const float*)d_in[9];
  const float* c1_v  = (const float*)d_in[10];
  const float* c2_w  = (const float*)d_in[11];
  const float* c2_g  = (const float*)d_in[12];
  const float* c2_b  = (const float*)d_in[13];
  const float* c2_m  = (const float*)d_in[14];
  const float* c2_v  = (const float*)d_in[15];
  float* out = (float*)d_out;

  float* qkv   = (float*)d_ws;                     // NB*QC*HW   = 9,437,184 f
  float* fused = qkv + (size_t)NB * QC * HW;       // NB*CH*HW   = 4,718,592 f

  qkv_conv  <<<dim3(9, 64, 8),  256, 0, stream>>>(x, qkv_w, qkv_g, qkv_b, qkv_m, qkv_v, qkv);
  flash_attn<<<dim3(9, NH, 8),  256, 0, stream>>>(qkv, fused);
  dwconv_add<<<dim3(9, CH, 8),  256, 0, stream>>>(qkv, c1_w, c1_g, c1_b, c1_m, c1_v, fused);
  c2_conv   <<<dim3(9, 32, 8),  256, 0, stream>>>(fused, c2_w, c2_g, c2_b, c2_m, c2_v, out);
}

// Round 2
// 495.204 us; speedup vs baseline: 6.4292x; 6.4292x over previous
//
#include <hip/hip_runtime.h>
#include <math.h>

#define HW 2304
#define NB 8
#define CH 256
#define QC 512
#define NH 4
#define DK 32
#define DV 64
#define EPS 1e-3f

typedef __bf16 bf16;
typedef bf16 bf16x8 __attribute__((ext_vector_type(8)));
typedef bf16 bf16x4 __attribute__((ext_vector_type(4)));
typedef float f32x4 __attribute__((ext_vector_type(4)));

// ---------------- Kernel A: qkv = BN(conv1x1(x, qkv_w)) ----------------
// Emits: Qb bf16 [bh][i][k] (scale folded), Kb bf16 [bh][j][k],
//        Vb bf16 [bh][d][j], Vf fp32 [b][c][p]  (c = h*64+d)
// grid (9, 64, 8), block 256
__global__ __launch_bounds__(256) void qkv_conv(
    const float* __restrict__ x, const float* __restrict__ w,
    const float* __restrict__ g, const float* __restrict__ bt,
    const float* __restrict__ mn, const float* __restrict__ vr,
    bf16* __restrict__ Qb, bf16* __restrict__ Kb,
    bf16* __restrict__ Vb, float* __restrict__ Vf)
{
  __shared__ float ws[8][CH];
  const int t = threadIdx.x;
  const int co0 = blockIdx.y * 8;
  const int b = blockIdx.z;
  const int p = blockIdx.x * 256 + t;
  #pragma unroll
  for (int r = 0; r < 8; ++r) ws[r][t] = w[(size_t)(co0 + r) * CH + t];
  __syncthreads();
  const float* xb = x + ((size_t)b * CH) * HW + p;
  float acc[8] = {0.f,0.f,0.f,0.f,0.f,0.f,0.f,0.f};
  for (int ci = 0; ci < CH; ci += 4) {
    const float x0 = xb[(size_t)(ci + 0) * HW];
    const float x1 = xb[(size_t)(ci + 1) * HW];
    const float x2 = xb[(size_t)(ci + 2) * HW];
    const float x3 = xb[(size_t)(ci + 3) * HW];
    #pragma unroll
    for (int r = 0; r < 8; ++r) {
      const float4 wv = *reinterpret_cast<const float4*>(&ws[r][ci]);
      acc[r] = fmaf(wv.x, x0, acc[r]);
      acc[r] = fmaf(wv.y, x1, acc[r]);
      acc[r] = fmaf(wv.z, x2, acc[r]);
      acc[r] = fmaf(wv.w, x3, acc[r]);
    }
  }
  float o[8];
  #pragma unroll
  for (int r = 0; r < 8; ++r) {
    const int co = co0 + r;
    const float s = g[co] / sqrtf(vr[co] + EPS);
    o[r] = acc[r] * s + (bt[co] - mn[co] * s);
  }
  const int h = co0 >> 7;         // head
  const int r0 = co0 & 127;       // channel-within-head of first output
  const int bh = b * NH + h;
  if (r0 < DK) {                  // Q block: fold scale, token-major
    const float scale = 0.17677669529663687f;  // 32^-0.5
    bf16x8 pk;
    #pragma unroll
    for (int r = 0; r < 8; ++r) pk[r] = (bf16)(o[r] * scale);
    *reinterpret_cast<bf16x8*>(Qb + ((size_t)bh * HW + p) * DK + r0) = pk;
  } else if (r0 < 2 * DK) {       // K block: token-major
    bf16x8 pk;
    #pragma unroll
    for (int r = 0; r < 8; ++r) pk[r] = (bf16)o[r];
    *reinterpret_cast<bf16x8*>(Kb + ((size_t)bh * HW + p) * DK + (r0 - DK)) = pk;
  } else {                        // V block: channel-major bf16 + fp32
    const int d0 = r0 - 2 * DK;
    #pragma unroll
    for (int r = 0; r < 8; ++r) {
      const int d = d0 + r;
      Vb[((size_t)bh * DV + d) * HW + p] = (bf16)o[r];
      Vf[((size_t)b * CH + h * DV + d) * HW + p] = o[r];
    }
  }
}

// ---------------- Kernel B: MFMA flash attention ----------------
// One wave = 16 queries. S' = K·Q^T (rows j, cols i) via mfma_16x16x32_bf16:
// lane holds col i = l&15, rows j = (l>>4)*4+reg (+16*tile). Softmax reduce =
// lane-local + shfl_xor(16,32). P -> padded LDS [16][136]bf16 -> B-fragments
// for PV. V fragments contiguous from channel-major Vb.
// grid (36, 32), block 256 (4 independent waves)
__global__ __launch_bounds__(256) void flash_attn(
    const bf16* __restrict__ Qb, const bf16* __restrict__ Kb,
    const bf16* __restrict__ Vb, float* __restrict__ outp)
{
  __shared__ bf16 Plds[4][16][136];
  const int t = threadIdx.x;
  const int wv = t >> 6;
  const int l = t & 63;
  const int li = l & 15;        // query col i (within 16), also frag row
  const int gq = l >> 4;        // lane group 0..3
  const int bh = blockIdx.y;
  const int i0 = blockIdx.x * 64 + wv * 16;

  const bf16x8 qf = *reinterpret_cast<const bf16x8*>(
      Qb + ((size_t)bh * HW + i0 + li) * DK + gq * 8);
  const bf16* Kbase = Kb + (size_t)bh * HW * DK;
  const bf16* Vbase = Vb + (size_t)bh * DV * HW;

  f32x4 acc[4] = {{0.f,0.f,0.f,0.f},{0.f,0.f,0.f,0.f},
                  {0.f,0.f,0.f,0.f},{0.f,0.f,0.f,0.f}};
  float m_run = -INFINITY, l_run = 0.f;

  for (int j0 = 0; j0 < HW; j0 += 128) {
    f32x4 st[8];
    #pragma unroll
    for (int jt = 0; jt < 8; ++jt) {
      const bf16x8 kf = *reinterpret_cast<const bf16x8*>(
          Kbase + (size_t)(j0 + jt * 16 + li) * DK + gq * 8);
      st[jt] = __builtin_amdgcn_mfma_f32_16x16x32_bf16(
          kf, qf, (f32x4){0.f,0.f,0.f,0.f}, 0, 0, 0);
    }
    // row (i) max: lane-local 32 values then across the 4 lane groups
    float tm = -INFINITY;
    #pragma unroll
    for (int jt = 0; jt < 8; ++jt)
      #pragma unroll
      for (int r = 0; r < 4; ++r) tm = fmaxf(tm, st[jt][r]);
    tm = fmaxf(tm, __shfl_xor(tm, 16));
    tm = fmaxf(tm, __shfl_xor(tm, 32));
    const float mnew = fmaxf(m_run, tm);
    const float corr = __expf(m_run - mnew);   // 0 on first tile
    m_run = mnew;
    l_run *= corr;
    #pragma unroll
    for (int dt = 0; dt < 4; ++dt)
      #pragma unroll
      for (int r = 0; r < 4; ++r) acc[dt][r] *= corr;
    float ps = 0.f;
    #pragma unroll
    for (int jt = 0; jt < 8; ++jt) {
      bf16x4 pb;
      #pragma unroll
      for (int r = 0; r < 4; ++r) {
        const float pv = __expf(st[jt][r] - mnew);
        ps += pv;
        pb[r] = (bf16)pv;
      }
      // P[j = 16*jt + 4*gq + r][i = li]
      *reinterpret_cast<bf16x4*>(&Plds[wv][li][jt * 16 + gq * 4]) = pb;
    }
    ps += __shfl_xor(ps, 16);
    ps += __shfl_xor(ps, 32);
    l_run += ps;
    // PV: acc[dt] += V[dt*16+li][j] * P[j][i], K-dim j in chunks of 32
    #pragma unroll
    for (int kt = 0; kt < 4; ++kt) {
      const bf16x8 pf = *reinterpret_cast<const bf16x8*>(
          &Plds[wv][li][kt * 32 + gq * 8]);
      #pragma unroll
      for (int dt = 0; dt < 4; ++dt) {
        const bf16x8 vf = *reinterpret_cast<const bf16x8*>(
            Vbase + (size_t)(dt * 16 + li) * HW + j0 + kt * 32 + gq * 8);
        acc[dt] = __builtin_amdgcn_mfma_f32_16x16x32_bf16(vf, pf, acc[dt], 0, 0, 0);
      }
    }
  }
  const float inv = 1.f / l_run;
  const int b = bh >> 2, h = bh & 3;
  float* ob = outp + ((size_t)b * CH + h * DV) * HW + i0 + li;
  #pragma unroll
  for (int dt = 0; dt < 4; ++dt)
    #pragma unroll
    for (int r = 0; r < 4; ++r)
      ob[(size_t)(dt * 16 + gq * 4 + r) * HW] = acc[dt][r] * inv;
}

// ------------- Kernel C: io += BN(dwconv3x3(v)) (in-place add) -------------
// grid (9, CH, NB), block 256
__global__ __launch_bounds__(256) void dwconv_add(
    const float* __restrict__ vf, const float* __restrict__ w,
    const float* __restrict__ g, const float* __restrict__ bt,
    const float* __restrict__ mn, const float* __restrict__ vr,
    float* __restrict__ io)
{
  const int t = threadIdx.x;
  const int p = blockIdx.x * 256 + t;
  const int c = blockIdx.y;
  const int b = blockIdx.z;
  const int y = p / 48, xx = p - y * 48;
  const float* in = vf + ((size_t)b * CH + c) * HW;
  const float* wc = w + c * 9;
  float a = 0.f;
  #pragma unroll
  for (int ky = 0; ky < 3; ++ky) {
    const int yy = y + ky - 1;
    if (yy < 0 || yy >= 48) continue;
    #pragma unroll
    for (int kx = 0; kx < 3; ++kx) {
      const int x2 = xx + kx - 1;
      if (x2 < 0 || x2 >= 48) continue;
      a = fmaf(wc[ky * 3 + kx], in[yy * 48 + x2], a);
    }
  }
  const float s = g[c] / sqrtf(vr[c] + EPS);
  const size_t o = ((size_t)b * CH + c) * HW + p;
  io[o] += a * s + (bt[c] - mn[c] * s);
}

// ---------------- Kernel D: out = BN(conv1x1(io, c2_w)) ----------------
// grid (9, 32, 8), block 256
__global__ __launch_bounds__(256) void c2_conv(
    const float* __restrict__ in, const float* __restrict__ w,
    const float* __restrict__ g, const float* __restrict__ bt,
    const float* __restrict__ mn, const float* __restrict__ vr,
    float* __restrict__ out)
{
  __shared__ float ws[8][CH];
  const int t = threadIdx.x;
  const int co0 = blockIdx.y * 8;
  const int b = blockIdx.z;
  const int p = blockIdx.x * 256 + t;
  #pragma unroll
  for (int r = 0; r < 8; ++r) ws[r][t] = w[(size_t)(co0 + r) * CH + t];
  __syncthreads();
  const float* xb = in + ((size_t)b * CH) * HW + p;
  float acc[8] = {0.f,0.f,0.f,0.f,0.f,0.f,0.f,0.f};
  for (int ci = 0; ci < CH; ci += 4) {
    const float x0 = xb[(size_t)(ci + 0) * HW];
    const float x1 = xb[(size_t)(ci + 1) * HW];
    const float x2 = xb[(size_t)(ci + 2) * HW];
    const float x3 = xb[(size_t)(ci + 3) * HW];
    #pragma unroll
    for (int r = 0; r < 8; ++r) {
      const float4 wv = *reinterpret_cast<const float4*>(&ws[r][ci]);
      acc[r] = fmaf(wv.x, x0, acc[r]);
      acc[r] = fmaf(wv.y, x1, acc[r]);
      acc[r] = fmaf(wv.z, x2, acc[r]);
      acc[r] = fmaf(wv.w, x3, acc[r]);
    }
  }
  #pragma unroll
  for (int r = 0; r < 8; ++r) {
    const int co = co0 + r;
    const float s = g[co] / sqrtf(vr[co] + EPS);
    out[((size_t)b * CH + co) * HW + p] = acc[r] * s + (bt[co] - mn[co] * s);
  }
}

extern "C" void kernel_launch(void* const* d_in, const int* in_sizes, int n_in,
                              void* d_out, int out_size, void* d_ws, size_t ws_size,
                              hipStream_t stream)
{
  const float* x     = (const float*)d_in[0];
  const float* qkv_w = (const float*)d_in[1];
  const float* qkv_g = (const float*)d_in[2];
  const float* qkv_b = (const float*)d_in[3];
  const float* qkv_m = (const float*)d_in[4];
  const float* qkv_v = (const float*)d_in[5];
  const float* c1_w  = (const float*)d_in[6];
  const float* c1_g  = (const float*)d_in[7];
  const float* c1_b  = (const float*)d_in[8];
  const float* c1_m  = (const float*)d_in[9];
  const float* c1_v  = (const float*)d_in[10];
  const float* c2_w  = (const float*)d_in[11];
  const float* c2_g  = (const float*)d_in[12];
  const float* c2_b  = (const float*)d_in[13];
  const float* c2_m  = (const float*)d_in[14];
  const float* c2_v  = (const float*)d_in[15];
  float* out = (float*)d_out;

  // workspace layout (bytes):
  //   Qb  bf16  8*4*2304*32  = 4,718,592 B
  //   Kb  bf16  8*4*2304*32  = 4,718,592 B
  //   Vb  bf16  8*4*64*2304  = 9,437,184 B
  //   Vf  f32   8*256*2304   = 18,874,368 B
  //   fused f32 8*256*2304   = 18,874,368 B     total ~56.6 MB
  char* wp = (char*)d_ws;
  bf16* Qb = (bf16*)wp;                 wp += (size_t)NB * NH * HW * DK * 2;
  bf16* Kb = (bf16*)wp;                 wp += (size_t)NB * NH * HW * DK * 2;
  bf16* Vb = (bf16*)wp;                 wp += (size_t)NB * NH * DV * HW * 2;
  float* Vf = (float*)wp;               wp += (size_t)NB * CH * HW * 4;
  float* fused = (float*)wp;

  qkv_conv  <<<dim3(9, 64, 8), 256, 0, stream>>>(x, qkv_w, qkv_g, qkv_b, qkv_m, qkv_v,
                                                 Qb, Kb, Vb, Vf);
  flash_attn<<<dim3(36, 32),   256, 0, stream>>>(Qb, Kb, Vb, fused);
  dwconv_add<<<dim3(9, CH, 8), 256, 0, stream>>>(Vf, c1_w, c1_g, c1_b, c1_m, c1_v, fused);
  c2_conv   <<<dim3(9, 32, 8), 256, 0, stream>>>(fused, c2_w, c2_g, c2_b, c2_m, c2_v, out);
}

// Round 5
// 461.140 us; speedup vs baseline: 6.9041x; 1.0739x over previous
//
#include <hip/hip_runtime.h>
#include <math.h>

#define HW 2304
#define NB 8
#define CH 256
#define QC 512
#define NH 4
#define DK 32
#define DV 64
#define EPS 1e-3f

typedef __bf16 bf16;
typedef bf16 bf16x8 __attribute__((ext_vector_type(8)));
typedef bf16 bf16x4 __attribute__((ext_vector_type(4)));
typedef float f32x4 __attribute__((ext_vector_type(4)));

// scale * log2(e), folded into Q weights so softmax uses exp2 directly
#define QSC (0.17677669529663687f * 1.4426950408889634f)

// ---------------- wprep: fold BN into bf16 weights ----------------
// grid 512 x 256
__global__ __launch_bounds__(256) void wprep(
    const float* __restrict__ qkv_w, const float* __restrict__ qkv_g,
    const float* __restrict__ qkv_b, const float* __restrict__ qkv_m,
    const float* __restrict__ qkv_v,
    const float* __restrict__ c1_w, const float* __restrict__ c1_g,
    const float* __restrict__ c1_b, const float* __restrict__ c1_m,
    const float* __restrict__ c1_v,
    const float* __restrict__ c2_w, const float* __restrict__ c2_g,
    const float* __restrict__ c2_b, const float* __restrict__ c2_m,
    const float* __restrict__ c2_v,
    bf16* __restrict__ Wq, float* __restrict__ bq,
    bf16* __restrict__ W2, float* __restrict__ b2,
    float* __restrict__ W1)
{
  const int tid = blockIdx.x * 256 + threadIdx.x;  // 0..131071
  {
    const int co = tid >> 8;
    const float s = qkv_g[co] / sqrtf(qkv_v[co] + EPS);
    const float f = ((co & 127) < DK) ? QSC : 1.f;
    Wq[tid] = (bf16)(qkv_w[tid] * s * f);
  }
  if (tid < 65536) {
    const int co = tid >> 8;
    const float s = c2_g[co] / sqrtf(c2_v[co] + EPS);
    W2[tid] = (bf16)(c2_w[tid] * s);
  }
  if (tid < 2560) {
    const int c = tid / 10, k = tid - c * 10;
    const float s = c1_g[c] / sqrtf(c1_v[c] + EPS);
    float v;
    if (k < 9) v = c1_w[c * 9 + k] * s;
    else       v = c1_b[c] - c1_m[c] * s;
    W1[tid] = v;
  }
  if (tid < QC) {
    const float s = qkv_g[tid] / sqrtf(qkv_v[tid] + EPS);
    const float f = ((tid & 127) < DK) ? QSC : 1.f;
    bq[tid] = (qkv_b[tid] - qkv_m[tid] * s) * f;
  }
  if (tid < CH) {
    const float s = c2_g[tid] / sqrtf(c2_v[tid] + EPS);
    b2[tid] = c2_b[tid] - c2_m[tid] * s;
  }
}

// ---------------- xprep: x fp32 [b][ci][p] -> Xt bf16 [b][p][ci] ----------------
// grid (36, 4, 8) x 256; tile 64ci x 64p via padded LDS
__global__ __launch_bounds__(256) void xprep(
    const float* __restrict__ x, bf16* __restrict__ Xt)
{
  __shared__ float T[64][65];
  const int t = threadIdx.x;
  const int p0 = blockIdx.x * 64;
  const int ci0 = blockIdx.y * 64;
  const int b = blockIdx.z;
  #pragma unroll
  for (int r = 0; r < 4; ++r) {         // 1024 float4s = 64ci x 16 chunks
    const int e = t + 256 * r;
    const int ci = e >> 4, p4 = (e & 15) * 4;
    const float4 v = *reinterpret_cast<const float4*>(
        x + ((size_t)(b * CH + ci0 + ci)) * HW + p0 + p4);
    T[ci][p4 + 0] = v.x; T[ci][p4 + 1] = v.y;
    T[ci][p4 + 2] = v.z; T[ci][p4 + 3] = v.w;
  }
  __syncthreads();
  #pragma unroll
  for (int r = 0; r < 2; ++r) {
    const int e = t + 256 * r;          // 0..511 8-chunks
    const int p = e >> 3, c8 = (e & 7) * 8;
    bf16x8 pk;
    #pragma unroll
    for (int j = 0; j < 8; ++j) pk[j] = (bf16)T[c8 + j][p];
    *reinterpret_cast<bf16x8*>(Xt + ((size_t)b * HW + p0 + p) * CH + ci0 + c8) = pk;
  }
}

// ---------------- qkv_gemm: [512 co] x [256 ci] x [64 p] tiles ----------------
// Emits Qb/Kb token-major [bh][tok][32] (scale+log2e folded in Wq), Vb [bh][d][tok].
// grid (36, 8, 8) x 256 (4 waves, no barriers, no LDS)
__global__ __launch_bounds__(256) void qkv_gemm(
    const bf16* __restrict__ Xt, const bf16* __restrict__ Wq,
    const float* __restrict__ bq,
    bf16* __restrict__ Qb, bf16* __restrict__ Kb, bf16* __restrict__ Vb)
{
  const int t = threadIdx.x;
  const int wv = t >> 6, l = t & 63, li = l & 15, g = l >> 4;
  const int cow = blockIdx.y * 64 + wv * 16;
  const int p0 = blockIdx.x * 64;
  const int b = blockIdx.z;
  const bf16* Bb = Xt + ((size_t)b * HW + p0) * CH;
  const bf16* Ab = Wq + (size_t)(cow + li) * CH + g * 8;
  f32x4 acc[4] = {{0.f,0.f,0.f,0.f},{0.f,0.f,0.f,0.f},
                  {0.f,0.f,0.f,0.f},{0.f,0.f,0.f,0.f}};
  #pragma unroll
  for (int k0 = 0; k0 < CH; k0 += 32) {
    const bf16x8 af = *reinterpret_cast<const bf16x8*>(Ab + k0);
    #pragma unroll
    for (int pt = 0; pt < 4; ++pt) {
      const bf16x8 bfr = *reinterpret_cast<const bf16x8*>(
          Bb + (size_t)(pt * 16 + li) * CH + k0 + g * 8);
      acc[pt] = __builtin_amdgcn_mfma_f32_16x16x32_bf16(af, bfr, acc[pt], 0, 0, 0);
    }
  }
  // lane holds D[co = cow + g*4 + r][p = p0 + pt*16 + li]
  const float4 bv = *reinterpret_cast<const float4*>(bq + cow + g * 4);
  const int r0 = cow & 127;
  const int h = cow >> 7;
  const int bh = b * NH + h;
  if (r0 < 2 * DK) {                    // Q or K: token-major
    bf16* dst = (r0 < DK) ? Qb : Kb;
    const int kk0 = (r0 & 31) + g * 4;
    #pragma unroll
    for (int pt = 0; pt < 4; ++pt) {
      bf16x4 pk;
      pk[0] = (bf16)(acc[pt][0] + bv.x); pk[1] = (bf16)(acc[pt][1] + bv.y);
      pk[2] = (bf16)(acc[pt][2] + bv.z); pk[3] = (bf16)(acc[pt][3] + bv.w);
      *reinterpret_cast<bf16x4*>(
          dst + ((size_t)bh * HW + p0 + pt * 16 + li) * DK + kk0) = pk;
    }
  } else {                              // V: channel-major
    const int d0 = (r0 - 2 * DK) + g * 4;
    #pragma unroll
    for (int pt = 0; pt < 4; ++pt) {
      const int p = p0 + pt * 16 + li;
      Vb[((size_t)bh * DV + d0 + 0) * HW + p] = (bf16)(acc[pt][0] + bv.x);
      Vb[((size_t)bh * DV + d0 + 1) * HW + p] = (bf16)(acc[pt][1] + bv.y);
      Vb[((size_t)bh * DV + d0 + 2) * HW + p] = (bf16)(acc[pt][2] + bv.z);
      Vb[((size_t)bh * DV + d0 + 3) * HW + p] = (bf16)(acc[pt][3] + bv.w);
    }
  }
}

// ---------------- flash_attn + fused dwconv epilogue ----------------
// Core identical to R2 (passing) but in exp2 domain (scale*log2e folded in Q).
// Epilogue: out = attn/l + BN(dwconv3x3(v)) written bf16 token-major F[b][tok][c].
// grid (36, 32) x 256 (4 waves x 16 queries)
__global__ __launch_bounds__(256) void flash_attn(
    const bf16* __restrict__ Qb, const bf16* __restrict__ Kb,
    const bf16* __restrict__ Vb, const float* __restrict__ W1,
    bf16* __restrict__ F)
{
  __shared__ bf16 Plds[4][16][136];
  __shared__ float wdw[DV][10];
  const int t = threadIdx.x;
  const int wv = t >> 6;
  const int l = t & 63;
  const int li = l & 15;
  const int gq = l >> 4;
  const int bh = blockIdx.y;
  const int b = bh >> 2, h = bh & 3;
  const int i0 = blockIdx.x * 64 + wv * 16;

  for (int e = t; e < DV * 10; e += 256) {
    const int d = e / 10, k = e - d * 10;
    wdw[d][k] = W1[(h * DV + d) * 10 + k];
  }
  __syncthreads();

  const bf16x8 qf = *reinterpret_cast<const bf16x8*>(
      Qb + ((size_t)bh * HW + i0 + li) * DK + gq * 8);
  const bf16* Kbase = Kb + (size_t)bh * HW * DK;
  const bf16* Vbase = Vb + (size_t)bh * DV * HW;

  f32x4 acc[4] = {{0.f,0.f,0.f,0.f},{0.f,0.f,0.f,0.f},
                  {0.f,0.f,0.f,0.f},{0.f,0.f,0.f,0.f}};
  float m_run = -INFINITY, l_run = 0.f;

  for (int j0 = 0; j0 < HW; j0 += 128) {
    f32x4 st[8];
    #pragma unroll
    for (int jt = 0; jt < 8; ++jt) {
      const bf16x8 kf = *reinterpret_cast<const bf16x8*>(
          Kbase + (size_t)(j0 + jt * 16 + li) * DK + gq * 8);
      st[jt] = __builtin_amdgcn_mfma_f32_16x16x32_bf16(
          kf, qf, (f32x4){0.f,0.f,0.f,0.f}, 0, 0, 0);
    }
    float tm = -INFINITY;
    #pragma unroll
    for (int jt = 0; jt < 8; ++jt)
      #pragma unroll
      for (int r = 0; r < 4; ++r) tm = fmaxf(tm, st[jt][r]);
    tm = fmaxf(tm, __shfl_xor(tm, 16));
    tm = fmaxf(tm, __shfl_xor(tm, 32));
    const float mnew = fmaxf(m_run, tm);
    const float corr = __builtin_exp2f(m_run - mnew);
    m_run = mnew;
    l_run *= corr;
    #pragma unroll
    for (int dt = 0; dt < 4; ++dt)
      #pragma unroll
      for (int r = 0; r < 4; ++r) acc[dt][r] *= corr;
    float ps = 0.f;
    #pragma unroll
    for (int jt = 0; jt < 8; ++jt) {
      bf16x4 pb;
      #pragma unroll
      for (int r = 0; r < 4; ++r) {
        const float pv = __builtin_exp2f(st[jt][r] - mnew);
        ps += pv;
        pb[r] = (bf16)pv;
      }
      *reinterpret_cast<bf16x4*>(&Plds[wv][li][jt * 16 + gq * 4]) = pb;
    }
    ps += __shfl_xor(ps, 16);
    ps += __shfl_xor(ps, 32);
    l_run += ps;
    #pragma unroll
    for (int kt = 0; kt < 4; ++kt) {
      const bf16x8 pf = *reinterpret_cast<const bf16x8*>(
          &Plds[wv][li][kt * 32 + gq * 8]);
      #pragma unroll
      for (int dt = 0; dt < 4; ++dt) {
        const bf16x8 vf = *reinterpret_cast<const bf16x8*>(
            Vbase + (size_t)(dt * 16 + li) * HW + j0 + kt * 32 + gq * 8);
        acc[dt] = __builtin_amdgcn_mfma_f32_16x16x32_bf16(vf, pf, acc[dt], 0, 0, 0);
      }
    }
  }
  // epilogue: normalize + dwconv(v) + write bf16 token-major
  const float inv = 1.f / l_run;
  const int i = i0 + li;
  const int y = i / 48, xx = i - y * 48;
  bf16* Fo = F + ((size_t)b * HW + i) * CH + h * DV;
  #pragma unroll
  for (int dt = 0; dt < 4; ++dt) {
    bf16x4 pk;
    #pragma unroll
    for (int r = 0; r < 4; ++r) {
      const int d = dt * 16 + gq * 4 + r;
      const bf16* vrow = Vbase + (size_t)d * HW;
      float a = wdw[d][9];
      #pragma unroll
      for (int ky = 0; ky < 3; ++ky) {
        const int yy = y + ky - 1;
        const bool vy = (unsigned)yy < 48u;
        const int yc = vy ? yy : y;
        #pragma unroll
        for (int kx = 0; kx < 3; ++kx) {
          const int x2 = xx + kx - 1;
          const bool vx = (unsigned)x2 < 48u;
          const float wk = (vy && vx) ? wdw[d][ky * 3 + kx] : 0.f;
          const int nb = yc * 48 + (vx ? x2 : xx);
          a = fmaf(wk, (float)vrow[nb], a);
        }
      }
      pk[r] = (bf16)(acc[dt][r] * inv + a);
    }
    *reinterpret_cast<bf16x4*>(Fo + dt * 16 + gq * 4) = pk;
  }
}

// ---------------- c2_gemm: out = W2 . F + b2, fp32 out [b][co][p] ----------------
// grid (36, 4, 8) x 256
__global__ __launch_bounds__(256) void c2_gemm(
    const bf16* __restrict__ F, const bf16* __restrict__ W2,
    const float* __restrict__ b2, float* __restrict__ out)
{
  const int t = threadIdx.x;
  const int wv = t >> 6, l = t & 63, li = l & 15, g = l >> 4;
  const int cow = blockIdx.y * 64 + wv * 16;
  const int p0 = blockIdx.x * 64;
  const int b = blockIdx.z;
  const bf16* Bb = F + ((size_t)b * HW + p0) * CH;
  const bf16* Ab = W2 + (size_t)(cow + li) * CH + g * 8;
  f32x4 acc[4] = {{0.f,0.f,0.f,0.f},{0.f,0.f,0.f,0.f},
                  {0.f,0.f,0.f,0.f},{0.f,0.f,0.f,0.f}};
  #pragma unroll
  for (int k0 = 0; k0 < CH; k0 += 32) {
    const bf16x8 af = *reinterpret_cast<const bf16x8*>(Ab + k0);
    #pragma unroll
    for (int pt = 0; pt < 4; ++pt) {
      const bf16x8 bfr = *reinterpret_cast<const bf16x8*>(
          Bb + (size_t)(pt * 16 + li) * CH + k0 + g * 8);
      acc[pt] = __builtin_amdgcn_mfma_f32_16x16x32_bf16(af, bfr, acc[pt], 0, 0, 0);
    }
  }
  const float4 bv = *reinterpret_cast<const float4*>(b2 + cow + g * 4);
  #pragma unroll
  for (int pt = 0; pt < 4; ++pt) {
    const int p = p0 + pt * 16 + li;
    float* ob = out + ((size_t)b * CH + cow + g * 4) * HW + p;
    ob[0 * HW] = acc[pt][0] + bv.x;
    ob[1 * HW] = acc[pt][1] + bv.y;
    ob[2 * HW] = acc[pt][2] + bv.z;
    ob[3 * HW] = acc[pt][3] + bv.w;
  }
}

extern "C" void kernel_launch(void* const* d_in, const int* in_sizes, int n_in,
                              void* d_out, int out_size, void* d_ws, size_t ws_size,
                              hipStream_t stream)
{
  const float* x     = (const float*)d_in[0];
  const float* qkv_w = (const float*)d_in[1];
  const float* qkv_g = (const float*)d_in[2];
  const float* qkv_b = (const float*)d_in[3];
  const float* qkv_m = (const float*)d_in[4];
  const float* qkv_v = (const float*)d_in[5];
  const float* c1_w  = (const float*)d_in[6];
  const float* c1_g  = (const float*)d_in[7];
  const float* c1_b  = (const float*)d_in[8];
  const float* c1_m  = (const float*)d_in[9];
  const float* c1_v  = (const float*)d_in[10];
  const float* c2_w  = (const float*)d_in[11];
  const float* c2_g  = (const float*)d_in[12];
  const float* c2_b  = (const float*)d_in[13];
  const float* c2_m  = (const float*)d_in[14];
  const float* c2_v  = (const float*)d_in[15];
  float* out = (float*)d_out;

  char* wp = (char*)d_ws;
  bf16* Qb = (bf16*)wp;  wp += (size_t)NB * NH * HW * DK * 2;   //  4.7 MB
  bf16* Kb = (bf16*)wp;  wp += (size_t)NB * NH * HW * DK * 2;   //  4.7 MB
  bf16* Vb = (bf16*)wp;  wp += (size_t)NB * NH * DV * HW * 2;   //  9.4 MB
  bf16* Xt = (bf16*)wp;  wp += (size_t)NB * HW * CH * 2;        //  9.4 MB
  bf16* F  = (bf16*)wp;  wp += (size_t)NB * HW * CH * 2;        //  9.4 MB
  bf16* Wq = (bf16*)wp;  wp += (size_t)QC * CH * 2;
  bf16* W2 = (bf16*)wp;  wp += (size_t)CH * CH * 2;
  float* bq = (float*)wp; wp += QC * 4;
  float* b2 = (float*)wp; wp += CH * 4;
  float* W1 = (float*)wp; wp += CH * 10 * 4;

  wprep<<<dim3(512), 256, 0, stream>>>(qkv_w, qkv_g, qkv_b, qkv_m, qkv_v,
                                       c1_w, c1_g, c1_b, c1_m, c1_v,
                                       c2_w, c2_g, c2_b, c2_m, c2_v,
                                       Wq, bq, W2, b2, W1);
  xprep<<<dim3(36, 4, 8), 256, 0, stream>>>(x, Xt);
  qkv_gemm<<<dim3(36, 8, 8), 256, 0, stream>>>(Xt, Wq, bq, Qb, Kb, Vb);
  flash_attn<<<dim3(36, 32), 256, 0, stream>>>(Qb, Kb, Vb, W1, F);
  c2_gemm<<<dim3(36, 4, 8), 256, 0, stream>>>(F, W2, b2, out);
}

// Round 12
// 388.880 us; speedup vs baseline: 8.1870x; 1.1858x over previous
//
#include <hip/hip_runtime.h>
#include <math.h>

#define HW 2304
#define NB 8
#define CH 256
#define QC 512
#define NH 4
#define DK 32
#define DV 64
#define EPS 1e-3f

typedef __bf16 bf16;
typedef bf16 bf16x8 __attribute__((ext_vector_type(8)));
typedef bf16 bf16x4 __attribute__((ext_vector_type(4)));
typedef float f32x4 __attribute__((ext_vector_type(4)));

// scale * log2(e), folded into Q weights so softmax uses exp2 directly
#define QSC (0.17677669529663687f * 1.4426950408889634f)

// ---------------- wprep: fold BN into bf16 weights ----------------
// grid 512 x 256
__global__ __launch_bounds__(256) void wprep(
    const float* __restrict__ qkv_w, const float* __restrict__ qkv_g,
    const float* __restrict__ qkv_b, const float* __restrict__ qkv_m,
    const float* __restrict__ qkv_v,
    const float* __restrict__ c1_w, const float* __restrict__ c1_g,
    const float* __restrict__ c1_b, const float* __restrict__ c1_m,
    const float* __restrict__ c1_v,
    const float* __restrict__ c2_w, const float* __restrict__ c2_g,
    const float* __restrict__ c2_b, const float* __restrict__ c2_m,
    const float* __restrict__ c2_v,
    bf16* __restrict__ Wq, float* __restrict__ bq,
    bf16* __restrict__ W2, float* __restrict__ b2,
    float* __restrict__ W1)
{
  const int tid = blockIdx.x * 256 + threadIdx.x;  // 0..131071
  {
    const int co = tid >> 8;
    const float s = qkv_g[co] / sqrtf(qkv_v[co] + EPS);
    const float f = ((co & 127) < DK) ? QSC : 1.f;
    Wq[tid] = (bf16)(qkv_w[tid] * s * f);
  }
  if (tid < 65536) {
    const int co = tid >> 8;
    const float s = c2_g[co] / sqrtf(c2_v[co] + EPS);
    W2[tid] = (bf16)(c2_w[tid] * s);
  }
  if (tid < 2560) {
    const int c = tid / 10, k = tid - c * 10;
    const float s = c1_g[c] / sqrtf(c1_v[c] + EPS);
    float v;
    if (k < 9) v = c1_w[c * 9 + k] * s;
    else       v = c1_b[c] - c1_m[c] * s;
    W1[tid] = v;
  }
  if (tid < QC) {
    const float s = qkv_g[tid] / sqrtf(qkv_v[tid] + EPS);
    const float f = ((tid & 127) < DK) ? QSC : 1.f;
    bq[tid] = (qkv_b[tid] - qkv_m[tid] * s) * f;
  }
  if (tid < CH) {
    const float s = c2_g[tid] / sqrtf(c2_v[tid] + EPS);
    b2[tid] = c2_b[tid] - c2_m[tid] * s;
  }
}

// ---------------- xprep: x fp32 [b][ci][p] -> Xt bf16 [b][p][ci] ----------------
// grid (36, 4, 8) x 256; tile 64ci x 64p via padded LDS
__global__ __launch_bounds__(256) void xprep(
    const float* __restrict__ x, bf16* __restrict__ Xt)
{
  __shared__ float T[64][65];
  const int t = threadIdx.x;
  const int p0 = blockIdx.x * 64;
  const int ci0 = blockIdx.y * 64;
  const int b = blockIdx.z;
  #pragma unroll
  for (int r = 0; r < 4; ++r) {         // 1024 float4s = 64ci x 16 chunks
    const int e = t + 256 * r;
    const int ci = e >> 4, p4 = (e & 15) * 4;
    const float4 v = *reinterpret_cast<const float4*>(
        x + ((size_t)(b * CH + ci0 + ci)) * HW + p0 + p4);
    T[ci][p4 + 0] = v.x; T[ci][p4 + 1] = v.y;
    T[ci][p4 + 2] = v.z; T[ci][p4 + 3] = v.w;
  }
  __syncthreads();
  #pragma unroll
  for (int r = 0; r < 2; ++r) {
    const int e = t + 256 * r;          // 0..511 8-chunks
    const int p = e >> 3, c8 = (e & 7) * 8;
    bf16x8 pk;
    #pragma unroll
    for (int j = 0; j < 8; ++j) pk[j] = (bf16)T[c8 + j][p];
    *reinterpret_cast<bf16x8*>(Xt + ((size_t)b * HW + p0 + p) * CH + ci0 + c8) = pk;
  }
}

// ---------------- qkv_gemm: [512 co] x [256 ci] x [64 p] tiles ----------------
// Emits Qb/Kb token-major [bh][tok][32] (scale+log2e folded in Wq), Vb [bh][d][tok].
// grid (36, 8, 8) x 256 (4 waves, no barriers, no LDS)
__global__ __launch_bounds__(256) void qkv_gemm(
    const bf16* __restrict__ Xt, const bf16* __restrict__ Wq,
    const float* __restrict__ bq,
    bf16* __restrict__ Qb, bf16* __restrict__ Kb, bf16* __restrict__ Vb)
{
  const int t = threadIdx.x;
  const int wv = t >> 6, l = t & 63, li = l & 15, g = l >> 4;
  const int cow = blockIdx.y * 64 + wv * 16;
  const int p0 = blockIdx.x * 64;
  const int b = blockIdx.z;
  const bf16* Bb = Xt + ((size_t)b * HW + p0) * CH;
  const bf16* Ab = Wq + (size_t)(cow + li) * CH + g * 8;
  f32x4 acc[4] = {{0.f,0.f,0.f,0.f},{0.f,0.f,0.f,0.f},
                  {0.f,0.f,0.f,0.f},{0.f,0.f,0.f,0.f}};
  #pragma unroll
  for (int k0 = 0; k0 < CH; k0 += 32) {
    const bf16x8 af = *reinterpret_cast<const bf16x8*>(Ab + k0);
    #pragma unroll
    for (int pt = 0; pt < 4; ++pt) {
      const bf16x8 bfr = *reinterpret_cast<const bf16x8*>(
          Bb + (size_t)(pt * 16 + li) * CH + k0 + g * 8);
      acc[pt] = __builtin_amdgcn_mfma_f32_16x16x32_bf16(af, bfr, acc[pt], 0, 0, 0);
    }
  }
  // lane holds D[co = cow + g*4 + r][p = p0 + pt*16 + li]
  const float4 bv = *reinterpret_cast<const float4*>(bq + cow + g * 4);
  const int r0 = cow & 127;
  const int h = cow >> 7;
  const int bh = b * NH + h;
  if (r0 < 2 * DK) {                    // Q or K: token-major
    bf16* dst = (r0 < DK) ? Qb : Kb;
    const int kk0 = (r0 & 31) + g * 4;
    #pragma unroll
    for (int pt = 0; pt < 4; ++pt) {
      bf16x4 pk;
      pk[0] = (bf16)(acc[pt][0] + bv.x); pk[1] = (bf16)(acc[pt][1] + bv.y);
      pk[2] = (bf16)(acc[pt][2] + bv.z); pk[3] = (bf16)(acc[pt][3] + bv.w);
      *reinterpret_cast<bf16x4*>(
          dst + ((size_t)bh * HW + p0 + pt * 16 + li) * DK + kk0) = pk;
    }
  } else {                              // V: channel-major
    const int d0 = (r0 - 2 * DK) + g * 4;
    #pragma unroll
    for (int pt = 0; pt < 4; ++pt) {
      const int p = p0 + pt * 16 + li;
      Vb[((size_t)bh * DV + d0 + 0) * HW + p] = (bf16)(acc[pt][0] + bv.x);
      Vb[((size_t)bh * DV + d0 + 1) * HW + p] = (bf16)(acc[pt][1] + bv.y);
      Vb[((size_t)bh * DV + d0 + 2) * HW + p] = (bf16)(acc[pt][2] + bv.z);
      Vb[((size_t)bh * DV + d0 + 3) * HW + p] = (bf16)(acc[pt][3] + bv.w);
    }
  }
}

// ---------------- dwc: Dw = BN(dwconv3x3(V)) in channel-major bf16 ----------------
// Vb [bh*64+d][tok] -> Dw [bh*64+d][tok], bias included. Fully coalesced.
// grid 2304 x 256; thread = one 8-token chunk of one channel (48%8==0 -> chunks
// never cross image rows; 288 chunks per channel)
__global__ __launch_bounds__(256) void dwc(
    const bf16* __restrict__ Vb, const float* __restrict__ W1,
    bf16* __restrict__ Dw)
{
  const int gid = blockIdx.x * 256 + threadIdx.x;  // 0..589823
  const int c = gid / 288;                          // bh*64+d
  const int ck = gid - c * 288;
  const int p0 = ck * 8;
  const int y = p0 / 48, x0 = p0 - y * 48;          // x0 in {0,8,...,40}
  const float* wc = W1 + (c & 255) * 10;
  float w[9];
  #pragma unroll
  for (int k = 0; k < 9; ++k) w[k] = wc[k];
  float o[8];
  #pragma unroll
  for (int j = 0; j < 8; ++j) o[j] = wc[9];
  const bf16* vch = Vb + (size_t)c * HW;
  #pragma unroll
  for (int ky = 0; ky < 3; ++ky) {
    const int yy = y + ky - 1;
    if (yy < 0 || yy >= 48) continue;
    const bf16* row = vch + yy * 48 + x0;
    const bf16x8 mid = *reinterpret_cast<const bf16x8*>(row);
    float v[10];
    v[0] = (x0 > 0)  ? (float)row[-1] : 0.f;
    #pragma unroll
    for (int j = 0; j < 8; ++j) v[j + 1] = (float)mid[j];
    v[9] = (x0 < 40) ? (float)row[8]  : 0.f;
    #pragma unroll
    for (int kx = 0; kx < 3; ++kx) {
      const float wk = w[ky * 3 + kx];
      #pragma unroll
      for (int j = 0; j < 8; ++j) o[j] = fmaf(wk, v[j + kx], o[j]);
    }
  }
  bf16x8 pk;
  #pragma unroll
  for (int j = 0; j < 8; ++j) pk[j] = (bf16)o[j];
  *reinterpret_cast<bf16x8*>(Dw + (size_t)c * HW + p0) = pk;
}

// ---------------- flash_attn: j-split x2, K-prefetch, combine in LDS ----------------
// 512 threads = 8 waves. Wave wv: i-tile it=wv&3 (16 queries), j-half jh=wv>>2.
// Each wave runs the R2 core over its 1152-token j-range with next-tile K
// fragments prefetched. Halves merged via LDS (exact online-softmax merge);
// jh==0 waves add the precomputed dwconv (Dw gather) and write F token-major.
// grid (36, 32) x 512
__global__ __launch_bounds__(512) void flash_attn(
    const bf16* __restrict__ Qb, const bf16* __restrict__ Kb,
    const bf16* __restrict__ Vb, const bf16* __restrict__ Dw,
    bf16* __restrict__ F)
{
  __shared__ bf16 Plds[8][16][136];   // 34816 B; combine buffer overlays after barrier
  const int t = threadIdx.x;
  const int wv = t >> 6;
  const int l = t & 63;
  const int li = l & 15;
  const int gq = l >> 4;
  const int it = wv & 3, jh = wv >> 2;
  const int bh = blockIdx.y;
  const int b = bh >> 2, h = bh & 3;
  const int i0 = blockIdx.x * 64 + it * 16;

  const bf16x8 qf = *reinterpret_cast<const bf16x8*>(
      Qb + ((size_t)bh * HW + i0 + li) * DK + gq * 8);
  const bf16* Kbase = Kb + (size_t)bh * HW * DK;
  const bf16* Vbase = Vb + (size_t)bh * DV * HW;

  f32x4 acc[4] = {{0.f,0.f,0.f,0.f},{0.f,0.f,0.f,0.f},
                  {0.f,0.f,0.f,0.f},{0.f,0.f,0.f,0.f}};
  float m_run = -INFINITY, l_run = 0.f;

  const int jbeg = jh * (HW / 2);
  const int jend = jbeg + (HW / 2);    // 9 tiles of 128

  // prefetch K fragments for first tile
  bf16x8 kc[8];
  #pragma unroll
  for (int jt = 0; jt < 8; ++jt)
    kc[jt] = *reinterpret_cast<const bf16x8*>(
        Kbase + (size_t)(jbeg + jt * 16 + li) * DK + gq * 8);

  for (int j0 = jbeg; j0 < jend; j0 += 128) {
    f32x4 st[8];
    #pragma unroll
    for (int jt = 0; jt < 8; ++jt)
      st[jt] = __builtin_amdgcn_mfma_f32_16x16x32_bf16(
          kc[jt], qf, (f32x4){0.f,0.f,0.f,0.f}, 0, 0, 0);
    // prefetch next tile's K (clamped dummy on last iter; stays in flight
    // across the softmax VALU phase)
    const int jn = (j0 + 128 < jend) ? (j0 + 128) : jbeg;
    #pragma unroll
    for (int jt = 0; jt < 8; ++jt)
      kc[jt] = *reinterpret_cast<const bf16x8*>(
          Kbase + (size_t)(jn + jt * 16 + li) * DK + gq * 8);

    float tm = -INFINITY;
    #pragma unroll
    for (int jt = 0; jt < 8; ++jt)
      #pragma unroll
      for (int r = 0; r < 4; ++r) tm = fmaxf(tm, st[jt][r]);
    tm = fmaxf(tm, __shfl_xor(tm, 16));
    tm = fmaxf(tm, __shfl_xor(tm, 32));
    const float mnew = fmaxf(m_run, tm);
    const float corr = __builtin_exp2f(m_run - mnew);
    m_run = mnew;
    l_run *= corr;
    #pragma unroll
    for (int dt = 0; dt < 4; ++dt)
      #pragma unroll
      for (int r = 0; r < 4; ++r) acc[dt][r] *= corr;
    float ps = 0.f;
    #pragma unroll
    for (int jt = 0; jt < 8; ++jt) {
      bf16x4 pb;
      #pragma unroll
      for (int r = 0; r < 4; ++r) {
        const float pv = __builtin_exp2f(st[jt][r] - mnew);
        ps += pv;
        pb[r] = (bf16)pv;
      }
      *reinterpret_cast<bf16x4*>(&Plds[wv][li][jt * 16 + gq * 4]) = pb;
    }
    ps += __shfl_xor(ps, 16);
    ps += __shfl_xor(ps, 32);
    l_run += ps;
    #pragma unroll
    for (int kt = 0; kt < 4; ++kt) {
      const bf16x8 pf = *reinterpret_cast<const bf16x8*>(
          &Plds[wv][li][kt * 32 + gq * 8]);
      #pragma unroll
      for (int dt = 0; dt < 4; ++dt) {
        const bf16x8 vf = *reinterpret_cast<const bf16x8*>(
            Vbase + (size_t)(dt * 16 + li) * HW + j0 + kt * 32 + gq * 8);
        acc[dt] = __builtin_amdgcn_mfma_f32_16x16x32_bf16(vf, pf, acc[dt], 0, 0, 0);
      }
    }
  }

  // ---- merge the two j-halves through LDS (overlays Plds) ----
  __syncthreads();                     // everyone done with Plds
  float* cacc = (float*)&Plds[0][0][0];        // [4][64][17]
  float* cml  = cacc + 4 * 64 * 17;            // [4][2][16]
  if (jh == 1) {
    float* dst = cacc + (wv - 4) * 64 * 17 + l * 17;
    #pragma unroll
    for (int dt = 0; dt < 4; ++dt)
      #pragma unroll
      for (int r = 0; r < 4; ++r) dst[dt * 4 + r] = acc[dt][r];
    if (gq == 0) {
      cml[(wv - 4) * 32 + li] = m_run;
      cml[(wv - 4) * 32 + 16 + li] = l_run;
    }
  }
  __syncthreads();
  if (jh == 0) {
    const float* src = cacc + wv * 64 * 17 + l * 17;
    const float mb = cml[wv * 32 + li];
    const float lb = cml[wv * 32 + 16 + li];
    const float m = fmaxf(m_run, mb);
    const float ca = __builtin_exp2f(m_run - m);
    const float cb = __builtin_exp2f(mb - m);
    const float linv = 1.f / (l_run * ca + lb * cb);
    const int i = i0 + li;
    const bf16* dwb = Dw + (size_t)bh * DV * HW + i;
    bf16* Fo = F + ((size_t)b * HW + i) * CH + h * DV;
    #pragma unroll
    for (int dt = 0; dt < 4; ++dt) {
      bf16x4 pk;
      #pragma unroll
      for (int r = 0; r < 4; ++r) {
        const int d = dt * 16 + gq * 4 + r;
        const float oa = (acc[dt][r] * ca + src[dt * 4 + r] * cb) * linv;
        pk[r] = (bf16)(oa + (float)dwb[(size_t)d * HW]);
      }
      *reinterpret_cast<bf16x4*>(Fo + dt * 16 + gq * 4) = pk;
    }
  }
}

// ---------------- c2_gemm: out = W2 . F + b2, fp32 out [b][co][p] ----------------
// grid (36, 4, 8) x 256
__global__ __launch_bounds__(256) void c2_gemm(
    const bf16* __restrict__ F, const bf16* __restrict__ W2,
    const float* __restrict__ b2, float* __restrict__ out)
{
  const int t = threadIdx.x;
  const int wv = t >> 6, l = t & 63, li = l & 15, g = l >> 4;
  const int cow = blockIdx.y * 64 + wv * 16;
  const int p0 = blockIdx.x * 64;
  const int b = blockIdx.z;
  const bf16* Bb = F + ((size_t)b * HW + p0) * CH;
  const bf16* Ab = W2 + (size_t)(cow + li) * CH + g * 8;
  f32x4 acc[4] = {{0.f,0.f,0.f,0.f},{0.f,0.f,0.f,0.f},
                  {0.f,0.f,0.f,0.f},{0.f,0.f,0.f,0.f}};
  #pragma unroll
  for (int k0 = 0; k0 < CH; k0 += 32) {
    const bf16x8 af = *reinterpret_cast<const bf16x8*>(Ab + k0);
    #pragma unroll
    for (int pt = 0; pt < 4; ++pt) {
      const bf16x8 bfr = *reinterpret_cast<const bf16x8*>(
          Bb + (size_t)(pt * 16 + li) * CH + k0 + g * 8);
      acc[pt] = __builtin_amdgcn_mfma_f32_16x16x32_bf16(af, bfr, acc[pt], 0, 0, 0);
    }
  }
  const float4 bv = *reinterpret_cast<const float4*>(b2 + cow + g * 4);
  #pragma unroll
  for (int pt = 0; pt < 4; ++pt) {
    const int p = p0 + pt * 16 + li;
    float* ob = out + ((size_t)b * CH + cow + g * 4) * HW + p;
    ob[0 * HW] = acc[pt][0] + bv.x;
    ob[1 * HW] = acc[pt][1] + bv.y;
    ob[2 * HW] = acc[pt][2] + bv.z;
    ob[3 * HW] = acc[pt][3] + bv.w;
  }
}

extern "C" void kernel_launch(void* const* d_in, const int* in_sizes, int n_in,
                              void* d_out, int out_size, void* d_ws, size_t ws_size,
                              hipStream_t stream)
{
  const float* x     = (const float*)d_in[0];
  const float* qkv_w = (const float*)d_in[1];
  const float* qkv_g = (const float*)d_in[2];
  const float* qkv_b = (const float*)d_in[3];
  const float* qkv_m = (const float*)d_in[4];
  const float* qkv_v = (const float*)d_in[5];
  const float* c1_w  = (const float*)d_in[6];
  const float* c1_g  = (const float*)d_in[7];
  const float* c1_b  = (const float*)d_in[8];
  const float* c1_m  = (const float*)d_in[9];
  const float* c1_v  = (const float*)d_in[10];
  const float* c2_w  = (const float*)d_in[11];
  const float* c2_g  = (const float*)d_in[12];
  const float* c2_b  = (const float*)d_in[13];
  const float* c2_m  = (const float*)d_in[14];
  const float* c2_v  = (const float*)d_in[15];
  float* out = (float*)d_out;

  char* wp = (char*)d_ws;
  bf16* Qb = (bf16*)wp;  wp += (size_t)NB * NH * HW * DK * 2;   //  4.7 MB
  bf16* Kb = (bf16*)wp;  wp += (size_t)NB * NH * HW * DK * 2;   //  4.7 MB
  bf16* Vb = (bf16*)wp;  wp += (size_t)NB * NH * DV * HW * 2;   //  9.4 MB
  bf16* Xt = (bf16*)wp;  wp += (size_t)NB * HW * CH * 2;        //  9.4 MB
  bf16* F  = (bf16*)wp;  wp += (size_t)NB * HW * CH * 2;        //  9.4 MB
  bf16* Dw = (bf16*)wp;  wp += (size_t)NB * NH * DV * HW * 2;   //  9.4 MB
  bf16* Wq = (bf16*)wp;  wp += (size_t)QC * CH * 2;
  bf16* W2 = (bf16*)wp;  wp += (size_t)CH * CH * 2;
  float* bq = (float*)wp; wp += QC * 4;
  float* b2 = (float*)wp; wp += CH * 4;
  float* W1 = (float*)wp; wp += CH * 10 * 4;

  wprep<<<dim3(512), 256, 0, stream>>>(qkv_w, qkv_g, qkv_b, qkv_m, qkv_v,
                                       c1_w, c1_g, c1_b, c1_m, c1_v,
                                       c2_w, c2_g, c2_b, c2_m, c2_v,
                                       Wq, bq, W2, b2, W1);
  xprep<<<dim3(36, 4, 8), 256, 0, stream>>>(x, Xt);
  qkv_gemm<<<dim3(36, 8, 8), 256, 0, stream>>>(Xt, Wq, bq, Qb, Kb, Vb);
  dwc<<<dim3(2304), 256, 0, stream>>>(Vb, W1, Dw);
  flash_attn<<<dim3(36, 32), 512, 0, stream>>>(Qb, Kb, Vb, Dw, F);
  c2_gemm<<<dim3(36, 4, 8), 256, 0, stream>>>(F, W2, b2, out);
}

// Round 14
// 386.644 us; speedup vs baseline: 8.2344x; 1.0058x over previous
//
#include <hip/hip_runtime.h>
#include <math.h>

#define HW 2304
#define NB 8
#define CH 256
#define QC 512
#define NH 4
#define DK 32
#define DV 64
#define EPS 1e-3f

typedef __bf16 bf16;
typedef bf16 bf16x8 __attribute__((ext_vector_type(8)));
typedef bf16 bf16x4 __attribute__((ext_vector_type(4)));
typedef float f32x4 __attribute__((ext_vector_type(4)));

// scale * log2(e), folded into Q weights so softmax uses exp2 directly
#define QSC (0.17677669529663687f * 1.4426950408889634f)

// ---------------- wprep: fold BN into bf16 weights ----------------
// grid 512 x 256
__global__ __launch_bounds__(256) void wprep(
    const float* __restrict__ qkv_w, const float* __restrict__ qkv_g,
    const float* __restrict__ qkv_b, const float* __restrict__ qkv_m,
    const float* __restrict__ qkv_v,
    const float* __restrict__ c1_w, const float* __restrict__ c1_g,
    const float* __restrict__ c1_b, const float* __restrict__ c1_m,
    const float* __restrict__ c1_v,
    const float* __restrict__ c2_w, const float* __restrict__ c2_g,
    const float* __restrict__ c2_b, const float* __restrict__ c2_m,
    const float* __restrict__ c2_v,
    bf16* __restrict__ Wq, float* __restrict__ bq,
    bf16* __restrict__ W2, float* __restrict__ b2,
    float* __restrict__ W1)
{
  const int tid = blockIdx.x * 256 + threadIdx.x;  // 0..131071
  {
    const int co = tid >> 8;
    const float s = qkv_g[co] / sqrtf(qkv_v[co] + EPS);
    const float f = ((co & 127) < DK) ? QSC : 1.f;
    Wq[tid] = (bf16)(qkv_w[tid] * s * f);
  }
  if (tid < 65536) {
    const int co = tid >> 8;
    const float s = c2_g[co] / sqrtf(c2_v[co] + EPS);
    W2[tid] = (bf16)(c2_w[tid] * s);
  }
  if (tid < 2560) {
    const int c = tid / 10, k = tid - c * 10;
    const float s = c1_g[c] / sqrtf(c1_v[c] + EPS);
    float v;
    if (k < 9) v = c1_w[c * 9 + k] * s;
    else       v = c1_b[c] - c1_m[c] * s;
    W1[tid] = v;
  }
  if (tid < QC) {
    const float s = qkv_g[tid] / sqrtf(qkv_v[tid] + EPS);
    const float f = ((tid & 127) < DK) ? QSC : 1.f;
    bq[tid] = (qkv_b[tid] - qkv_m[tid] * s) * f;
  }
  if (tid < CH) {
    const float s = c2_g[tid] / sqrtf(c2_v[tid] + EPS);
    b2[tid] = c2_b[tid] - c2_m[tid] * s;
  }
}

// ---------------- xprep: x fp32 [b][ci][p] -> Xt bf16 [b][p][ci] ----------------
// grid (36, 4, 8) x 256; tile 64ci x 64p via padded LDS
__global__ __launch_bounds__(256) void xprep(
    const float* __restrict__ x, bf16* __restrict__ Xt)
{
  __shared__ float T[64][65];
  const int t = threadIdx.x;
  const int p0 = blockIdx.x * 64;
  const int ci0 = blockIdx.y * 64;
  const int b = blockIdx.z;
  #pragma unroll
  for (int r = 0; r < 4; ++r) {         // 1024 float4s = 64ci x 16 chunks
    const int e = t + 256 * r;
    const int ci = e >> 4, p4 = (e & 15) * 4;
    const float4 v = *reinterpret_cast<const float4*>(
        x + ((size_t)(b * CH + ci0 + ci)) * HW + p0 + p4);
    T[ci][p4 + 0] = v.x; T[ci][p4 + 1] = v.y;
    T[ci][p4 + 2] = v.z; T[ci][p4 + 3] = v.w;
  }
  __syncthreads();
  #pragma unroll
  for (int r = 0; r < 2; ++r) {
    const int e = t + 256 * r;          // 0..511 8-chunks
    const int p = e >> 3, c8 = (e & 7) * 8;
    bf16x8 pk;
    #pragma unroll
    for (int j = 0; j < 8; ++j) pk[j] = (bf16)T[c8 + j][p];
    *reinterpret_cast<bf16x8*>(Xt + ((size_t)b * HW + p0 + p) * CH + ci0 + c8) = pk;
  }
}

// ---------------- qkv_gemm: [512 co] x [256 ci] x [64 p] tiles ----------------
// Emits Qb/Kb token-major [bh][tok][32] (scale+log2e folded in Wq), Vb [bh][d][tok].
// grid (36, 8, 8) x 256 (4 waves, no barriers, no LDS)
__global__ __launch_bounds__(256) void qkv_gemm(
    const bf16* __restrict__ Xt, const bf16* __restrict__ Wq,
    const float* __restrict__ bq,
    bf16* __restrict__ Qb, bf16* __restrict__ Kb, bf16* __restrict__ Vb)
{
  const int t = threadIdx.x;
  const int wv = t >> 6, l = t & 63, li = l & 15, g = l >> 4;
  const int cow = blockIdx.y * 64 + wv * 16;
  const int p0 = blockIdx.x * 64;
  const int b = blockIdx.z;
  const bf16* Bb = Xt + ((size_t)b * HW + p0) * CH;
  const bf16* Ab = Wq + (size_t)(cow + li) * CH + g * 8;
  f32x4 acc[4] = {{0.f,0.f,0.f,0.f},{0.f,0.f,0.f,0.f},
                  {0.f,0.f,0.f,0.f},{0.f,0.f,0.f,0.f}};
  #pragma unroll
  for (int k0 = 0; k0 < CH; k0 += 32) {
    const bf16x8 af = *reinterpret_cast<const bf16x8*>(Ab + k0);
    #pragma unroll
    for (int pt = 0; pt < 4; ++pt) {
      const bf16x8 bfr = *reinterpret_cast<const bf16x8*>(
          Bb + (size_t)(pt * 16 + li) * CH + k0 + g * 8);
      acc[pt] = __builtin_amdgcn_mfma_f32_16x16x32_bf16(af, bfr, acc[pt], 0, 0, 0);
    }
  }
  // lane holds D[co = cow + g*4 + r][p = p0 + pt*16 + li]
  const float4 bv = *reinterpret_cast<const float4*>(bq + cow + g * 4);
  const int r0 = cow & 127;
  const int h = cow >> 7;
  const int bh = b * NH + h;
  if (r0 < 2 * DK) {                    // Q or K: token-major
    bf16* dst = (r0 < DK) ? Qb : Kb;
    const int kk0 = (r0 & 31) + g * 4;
    #pragma unroll
    for (int pt = 0; pt < 4; ++pt) {
      bf16x4 pk;
      pk[0] = (bf16)(acc[pt][0] + bv.x); pk[1] = (bf16)(acc[pt][1] + bv.y);
      pk[2] = (bf16)(acc[pt][2] + bv.z); pk[3] = (bf16)(acc[pt][3] + bv.w);
      *reinterpret_cast<bf16x4*>(
          dst + ((size_t)bh * HW + p0 + pt * 16 + li) * DK + kk0) = pk;
    }
  } else {                              // V: channel-major
    const int d0 = (r0 - 2 * DK) + g * 4;
    #pragma unroll
    for (int pt = 0; pt < 4; ++pt) {
      const int p = p0 + pt * 16 + li;
      Vb[((size_t)bh * DV + d0 + 0) * HW + p] = (bf16)(acc[pt][0] + bv.x);
      Vb[((size_t)bh * DV + d0 + 1) * HW + p] = (bf16)(acc[pt][1] + bv.y);
      Vb[((size_t)bh * DV + d0 + 2) * HW + p] = (bf16)(acc[pt][2] + bv.z);
      Vb[((size_t)bh * DV + d0 + 3) * HW + p] = (bf16)(acc[pt][3] + bv.w);
    }
  }
}

// ---------------- dwc: Dw = BN(dwconv3x3(V)) in channel-major bf16 ----------------
// Vb [bh*64+d][tok] -> Dw [bh*64+d][tok], bias included. Fully coalesced.
// grid 2304 x 256
__global__ __launch_bounds__(256) void dwc(
    const bf16* __restrict__ Vb, const float* __restrict__ W1,
    bf16* __restrict__ Dw)
{
  const int gid = blockIdx.x * 256 + threadIdx.x;  // 0..589823
  const int c = gid / 288;                          // bh*64+d
  const int ck = gid - c * 288;
  const int p0 = ck * 8;
  const int y = p0 / 48, x0 = p0 - y * 48;          // x0 in {0,8,...,40}
  const float* wc = W1 + (c & 255) * 10;
  float w[9];
  #pragma unroll
  for (int k = 0; k < 9; ++k) w[k] = wc[k];
  float o[8];
  #pragma unroll
  for (int j = 0; j < 8; ++j) o[j] = wc[9];
  const bf16* vch = Vb + (size_t)c * HW;
  #pragma unroll
  for (int ky = 0; ky < 3; ++ky) {
    const int yy = y + ky - 1;
    if (yy < 0 || yy >= 48) continue;
    const bf16* row = vch + yy * 48 + x0;
    const bf16x8 mid = *reinterpret_cast<const bf16x8*>(row);
    float v[10];
    v[0] = (x0 > 0)  ? (float)row[-1] : 0.f;
    #pragma unroll
    for (int j = 0; j < 8; ++j) v[j + 1] = (float)mid[j];
    v[9] = (x0 < 40) ? (float)row[8]  : 0.f;
    #pragma unroll
    for (int kx = 0; kx < 3; ++kx) {
      const float wk = w[ky * 3 + kx];
      #pragma unroll
      for (int j = 0; j < 8; ++j) o[j] = fmaf(wk, v[j + kx], o[j]);
    }
  }
  bf16x8 pk;
  #pragma unroll
  for (int j = 0; j < 8; ++j) pk[j] = (bf16)o[j];
  *reinterpret_cast<bf16x8*>(Dw + (size_t)c * HW + p0) = pk;
}

// ---------------- flash_attn: j-split x2, K+V reg prefetch, combine in LDS ----------------
// 512 threads = 8 waves; wave = (i-tile it, j-half jh). __launch_bounds__(512,2)
// gives the allocator 256 VGPRs so kc[8] (next-tile K) and vc[16] (current-tile V,
// loaded before softmax so L2 latency hides under the VALU phase) stay in registers.
// grid (36, 32) x 512
__global__ __launch_bounds__(512, 2) void flash_attn(
    const bf16* __restrict__ Qb, const bf16* __restrict__ Kb,
    const bf16* __restrict__ Vb, const bf16* __restrict__ Dw,
    bf16* __restrict__ F)
{
  __shared__ bf16 Plds[8][16][136];   // 34816 B; combine buffer overlays after barrier
  const int t = threadIdx.x;
  const int wv = t >> 6;
  const int l = t & 63;
  const int li = l & 15;
  const int gq = l >> 4;
  const int it = wv & 3, jh = wv >> 2;
  const int bh = blockIdx.y;
  const int b = bh >> 2, h = bh & 3;
  const int i0 = blockIdx.x * 64 + it * 16;

  const bf16x8 qf = *reinterpret_cast<const bf16x8*>(
      Qb + ((size_t)bh * HW + i0 + li) * DK + gq * 8);
  const bf16* Kbase = Kb + (size_t)bh * HW * DK;
  const bf16* Vbase = Vb + (size_t)bh * DV * HW;

  f32x4 acc[4] = {{0.f,0.f,0.f,0.f},{0.f,0.f,0.f,0.f},
                  {0.f,0.f,0.f,0.f},{0.f,0.f,0.f,0.f}};
  float m_run = -INFINITY, l_run = 0.f;

  const int jbeg = jh * (HW / 2);
  const int jend = jbeg + (HW / 2);    // 9 tiles of 128

  // prefetch K fragments for first tile
  bf16x8 kc[8];
  #pragma unroll
  for (int jt = 0; jt < 8; ++jt)
    kc[jt] = *reinterpret_cast<const bf16x8*>(
        Kbase + (size_t)(jbeg + jt * 16 + li) * DK + gq * 8);

  for (int j0 = jbeg; j0 < jend; j0 += 128) {
    f32x4 st[8];
    #pragma unroll
    for (int jt = 0; jt < 8; ++jt)
      st[jt] = __builtin_amdgcn_mfma_f32_16x16x32_bf16(
          kc[jt], qf, (f32x4){0.f,0.f,0.f,0.f}, 0, 0, 0);
    // prefetch next tile's K (stays in flight across the softmax VALU phase)
    const int jn = (j0 + 128 < jend) ? (j0 + 128) : jbeg;
    #pragma unroll
    for (int jt = 0; jt < 8; ++jt)
      kc[jt] = *reinterpret_cast<const bf16x8*>(
          Kbase + (size_t)(jn + jt * 16 + li) * DK + gq * 8);
    // prefetch current tile's V into registers; latency hides under softmax
    bf16x8 vc[16];
    #pragma unroll
    for (int kt = 0; kt < 4; ++kt)
      #pragma unroll
      for (int dt = 0; dt < 4; ++dt)
        vc[kt * 4 + dt] = *reinterpret_cast<const bf16x8*>(
            Vbase + (size_t)(dt * 16 + li) * HW + j0 + kt * 32 + gq * 8);

    float tm = -INFINITY;
    #pragma unroll
    for (int jt = 0; jt < 8; ++jt)
      #pragma unroll
      for (int r = 0; r < 4; ++r) tm = fmaxf(tm, st[jt][r]);
    tm = fmaxf(tm, __shfl_xor(tm, 16));
    tm = fmaxf(tm, __shfl_xor(tm, 32));
    const float mnew = fmaxf(m_run, tm);
    const float corr = __builtin_exp2f(m_run - mnew);
    m_run = mnew;
    l_run *= corr;
    #pragma unroll
    for (int dt = 0; dt < 4; ++dt)
      #pragma unroll
      for (int r = 0; r < 4; ++r) acc[dt][r] *= corr;
    float ps = 0.f;
    #pragma unroll
    for (int jt = 0; jt < 8; ++jt) {
      bf16x4 pb;
      #pragma unroll
      for (int r = 0; r < 4; ++r) {
        const float pv = __builtin_exp2f(st[jt][r] - mnew);
        ps += pv;
        pb[r] = (bf16)pv;
      }
      *reinterpret_cast<bf16x4*>(&Plds[wv][li][jt * 16 + gq * 4]) = pb;
    }
    ps += __shfl_xor(ps, 16);
    ps += __shfl_xor(ps, 32);
    l_run += ps;
    #pragma unroll
    for (int kt = 0; kt < 4; ++kt) {
      const bf16x8 pf = *reinterpret_cast<const bf16x8*>(
          &Plds[wv][li][kt * 32 + gq * 8]);
      #pragma unroll
      for (int dt = 0; dt < 4; ++dt)
        acc[dt] = __builtin_amdgcn_mfma_f32_16x16x32_bf16(
            vc[kt * 4 + dt], pf, acc[dt], 0, 0, 0);
    }
  }

  // ---- merge the two j-halves through LDS (overlays Plds) ----
  __syncthreads();                     // everyone done with Plds
  float* cacc = (float*)&Plds[0][0][0];        // [4][64][17]
  float* cml  = cacc + 4 * 64 * 17;            // [4][2][16]
  if (jh == 1) {
    float* dst = cacc + (wv - 4) * 64 * 17 + l * 17;
    #pragma unroll
    for (int dt = 0; dt < 4; ++dt)
      #pragma unroll
      for (int r = 0; r < 4; ++r) dst[dt * 4 + r] = acc[dt][r];
    if (gq == 0) {
      cml[(wv - 4) * 32 + li] = m_run;
      cml[(wv - 4) * 32 + 16 + li] = l_run;
    }
  }
  __syncthreads();
  if (jh == 0) {
    const float* src = cacc + wv * 64 * 17 + l * 17;
    const float mb = cml[wv * 32 + li];
    const float lb = cml[wv * 32 + 16 + li];
    const float m = fmaxf(m_run, mb);
    const float ca = __builtin_exp2f(m_run - m);
    const float cb = __builtin_exp2f(mb - m);
    const float linv = 1.f / (l_run * ca + lb * cb);
    const int i = i0 + li;
    const bf16* dwb = Dw + (size_t)bh * DV * HW + i;
    bf16* Fo = F + ((size_t)b * HW + i) * CH + h * DV;
    #pragma unroll
    for (int dt = 0; dt < 4; ++dt) {
      bf16x4 pk;
      #pragma unroll
      for (int r = 0; r < 4; ++r) {
        const int d = dt * 16 + gq * 4 + r;
        const float oa = (acc[dt][r] * ca + src[dt * 4 + r] * cb) * linv;
        pk[r] = (bf16)(oa + (float)dwb[(size_t)d * HW]);
      }
      *reinterpret_cast<bf16x4*>(Fo + dt * 16 + gq * 4) = pk;
    }
  }
}

// ---------------- c2_gemm: out = W2 . F + b2, fp32 out [b][co][p] ----------------
// grid (36, 4, 8) x 256
__global__ __launch_bounds__(256) void c2_gemm(
    const bf16* __restrict__ F, const bf16* __restrict__ W2,
    const float* __restrict__ b2, float* __restrict__ out)
{
  const int t = threadIdx.x;
  const int wv = t >> 6, l = t & 63, li = l & 15, g = l >> 4;
  const int cow = blockIdx.y * 64 + wv * 16;
  const int p0 = blockIdx.x * 64;
  const int b = blockIdx.z;
  const bf16* Bb = F + ((size_t)b * HW + p0) * CH;
  const bf16* Ab = W2 + (size_t)(cow + li) * CH + g * 8;
  f32x4 acc[4] = {{0.f,0.f,0.f,0.f},{0.f,0.f,0.f,0.f},
                  {0.f,0.f,0.f,0.f},{0.f,0.f,0.f,0.f}};
  #pragma unroll
  for (int k0 = 0; k0 < CH; k0 += 32) {
    const bf16x8 af = *reinterpret_cast<const bf16x8*>(Ab + k0);
    #pragma unroll
    for (int pt = 0; pt < 4; ++pt) {
      const bf16x8 bfr = *reinterpret_cast<const bf16x8*>(
          Bb + (size_t)(pt * 16 + li) * CH + k0 + g * 8);
      acc[pt] = __builtin_amdgcn_mfma_f32_16x16x32_bf16(af, bfr, acc[pt], 0, 0, 0);
    }
  }
  const float4 bv = *reinterpret_cast<const float4*>(b2 + cow + g * 4);
  #pragma unroll
  for (int pt = 0; pt < 4; ++pt) {
    const int p = p0 + pt * 16 + li;
    float* ob = out + ((size_t)b * CH + cow + g * 4) * HW + p;
    ob[0 * HW] = acc[pt][0] + bv.x;
    ob[1 * HW] = acc[pt][1] + bv.y;
    ob[2 * HW] = acc[pt][2] + bv.z;
    ob[3 * HW] = acc[pt][3] + bv.w;
  }
}

extern "C" void kernel_launch(void* const* d_in, const int* in_sizes, int n_in,
                              void* d_out, int out_size, void* d_ws, size_t ws_size,
                              hipStream_t stream)
{
  const float* x     = (const float*)d_in[0];
  const float* qkv_w = (const float*)d_in[1];
  const float* qkv_g = (const float*)d_in[2];
  const float* qkv_b = (const float*)d_in[3];
  const float* qkv_m = (const float*)d_in[4];
  const float* qkv_v = (const float*)d_in[5];
  const float* c1_w  = (const float*)d_in[6];
  const float* c1_g  = (const float*)d_in[7];
  const float* c1_b  = (const float*)d_in[8];
  const float* c1_m  = (const float*)d_in[9];
  const float* c1_v  = (const float*)d_in[10];
  const float* c2_w  = (const float*)d_in[11];
  const float* c2_g  = (const float*)d_in[12];
  const float* c2_b  = (const float*)d_in[13];
  const float* c2_m  = (const float*)d_in[14];
  const float* c2_v  = (const float*)d_in[15];
  float* out = (float*)d_out;

  char* wp = (char*)d_ws;
  bf16* Qb = (bf16*)wp;  wp += (size_t)NB * NH * HW * DK * 2;   //  4.7 MB
  bf16* Kb = (bf16*)wp;  wp += (size_t)NB * NH * HW * DK * 2;   //  4.7 MB
  bf16* Vb = (bf16*)wp;  wp += (size_t)NB * NH * DV * HW * 2;   //  9.4 MB
  bf16* Xt = (bf16*)wp;  wp += (size_t)NB * HW * CH * 2;        //  9.4 MB
  bf16* F  = (bf16*)wp;  wp += (size_t)NB * HW * CH * 2;        //  9.4 MB
  bf16* Dw = (bf16*)wp;  wp += (size_t)NB * NH * DV * HW * 2;   //  9.4 MB
  bf16* Wq = (bf16*)wp;  wp += (size_t)QC * CH * 2;
  bf16* W2 = (bf16*)wp;  wp += (size_t)CH * CH * 2;
  float* bq = (float*)wp; wp += QC * 4;
  float* b2 = (float*)wp; wp += CH * 4;
  float* W1 = (float*)wp; wp += CH * 10 * 4;

  wprep<<<dim3(512), 256, 0, stream>>>(qkv_w, qkv_g, qkv_b, qkv_m, qkv_v,
                                       c1_w, c1_g, c1_b, c1_m, c1_v,
                                       c2_w, c2_g, c2_b, c2_m, c2_v,
                                       Wq, bq, W2, b2, W1);
  xprep<<<dim3(36, 4, 8), 256, 0, stream>>>(x, Xt);
  qkv_gemm<<<dim3(36, 8, 8), 256, 0, stream>>>(Xt, Wq, bq, Qb, Kb, Vb);
  dwc<<<dim3(2304), 256, 0, stream>>>(Vb, W1, Dw);
  flash_attn<<<dim3(36, 32), 512, 0, stream>>>(Qb, Kb, Vb, Dw, F);
  c2_gemm<<<dim3(36, 4, 8), 256, 0, stream>>>(F, W2, b2, out);
}